// Round 2
// baseline (515.856 us; speedup 1.0000x reference)
//
#include <hip/hip_runtime.h>
#include <cmath>

#define NB 32
#define NH 8
#define NL 2048
#define NE 64

// One block = 64 consecutive l-rows of one (b,h). 256 threads = 4 waves.
// Phase B: wave w -> d-range [16w,16w+16), lane -> row. k row held in
// registers pre-rotated by d0 so all FMA indices are compile-time.
// Phase D: wave w -> e-lane, rows 16w..16w+15; rotated v windows read
// DIRECTLY from global (256B row, L1-resident) -> zero LDS traffic.
__global__ __launch_bounds__(256, 4) void autocorr_kernel(
    const float* __restrict__ qg_,
    const float* __restrict__ kg_,
    const float* __restrict__ vg_,
    float* __restrict__ outV,   // (B,H,L,E)
    float* __restrict__ outC)   // (B,E,H,L)
{
    __shared__ alignas(16) float qb[64][64];   // q, granule-XOR swizzled
    __shared__ alignas(16) float kk[64][64];   // k, granule-XOR swizzled
    __shared__ float        cval[64][17];      // per-wave top-4 values
    __shared__ unsigned int cidx4[64][5];      // packed 4x u8 indices per wave
    __shared__ float4       wts4[64];          // softmaxed weights per row
    __shared__ unsigned int dpack[64];         // packed 4x u8 delays per row

    const int tid  = threadIdx.x;
    const int tile = blockIdx.x & 31;   // L/64 = 32 tiles
    const int bh   = blockIdx.x >> 5;   // b*H + h
    const int b    = bh >> 3;
    const int h    = bh & 7;
    const int l0   = tile * 64;
    const size_t rowbase = (size_t)bh * NL + l0;

    const float4* q4 = (const float4*)(qg_ + rowbase * NE);
    const float4* k4 = (const float4*)(kg_ + rowbase * NE);

    // ---- Phase A: stage q, k (coalesced float4), granule-XOR swizzle ----
    #pragma unroll
    for (int i = 0; i < 4; i++) {
        int idx = tid + i * 256;          // 0..1023 float4 = 64 rows x 16 granules
        int r = idx >> 4, g = idx & 15;
        int gs = (g ^ (r & 7)) * 4;
        float4 qv = q4[idx];
        float4 kv = k4[idx];
        *(float4*)&qb[r][gs] = qv;
        *(float4*)&kk[r][gs] = kv;
    }
    __syncthreads();

    const int wv = tid >> 6;   // wave id
    const int r  = tid & 63;   // row (lane)
    const int d0 = wv * 16;
    const int rq = r & 7;

    // ---- k row -> registers, pre-rotated: kreg[j] = k[(j - d0) & 63] ----
    float kreg[64];
    {
        const float* krow = &kk[r][0];
        #pragma unroll
        for (int m = 0; m < 16; m++) {
            int g = (((m - 4 * wv) & 15) ^ rq) * 4;
            float4 t = *(const float4*)(krow + g);
            kreg[4*m+0]=t.x; kreg[4*m+1]=t.y; kreg[4*m+2]=t.z; kreg[4*m+3]=t.w;
        }
    }

    // ---- Phase B: corr[d0+u] = sum_t q[t] * k[(t-d0-u) & 63] ----
    float acc[16];
    #pragma unroll
    for (int u = 0; u < 16; u++) acc[u] = 0.f;

    {
        const float* qrow = &qb[r][0];
        #pragma unroll
        for (int c = 0; c < 64; c += 16) {
            float qv[16];
            #pragma unroll
            for (int i = 0; i < 4; i++) {
                float4 t = *(const float4*)(qrow + (((c >> 2) + i) ^ rq) * 4);
                qv[i*4+0]=t.x; qv[i*4+1]=t.y; qv[i*4+2]=t.z; qv[i*4+3]=t.w;
            }
            #pragma unroll
            for (int u = 0; u < 16; u++) {
                #pragma unroll
                for (int tt = 0; tt < 16; tt++) {
                    acc[u] = fmaf(qv[tt], kreg[(c + tt - u) & 63], acc[u]);
                }
            }
        }
    }

    // corr -> transposed output (B,E,H,L); lane = l -> coalesced
    {
        float* oc = outC + ((size_t)(b * NE + d0) * NH + h) * NL + l0 + r;
        #pragma unroll
        for (int u = 0; u < 16; u++) {
            oc[(size_t)u * (NH * NL)] = acc[u];
        }
    }

    // per-thread top-4 of this thread's 16 corr values
    float bv[4] = {-3.0e38f, -3.0e38f, -3.0e38f, -3.0e38f};
    int   bi[4] = {0, 0, 0, 0};
    #pragma unroll
    for (int u = 0; u < 16; u++) {
        float x = acc[u]; int ix = d0 + u;
        if (x > bv[3]) {
            if (x > bv[1]) {
                if (x > bv[0]) { bv[3]=bv[2];bi[3]=bi[2]; bv[2]=bv[1];bi[2]=bi[1]; bv[1]=bv[0];bi[1]=bi[0]; bv[0]=x; bi[0]=ix; }
                else           { bv[3]=bv[2];bi[3]=bi[2]; bv[2]=bv[1];bi[2]=bi[1]; bv[1]=x; bi[1]=ix; }
            } else {
                if (x > bv[2]) { bv[3]=bv[2];bi[3]=bi[2]; bv[2]=x; bi[2]=ix; }
                else           { bv[3]=x; bi[3]=ix; }
            }
        }
    }
    #pragma unroll
    for (int j = 0; j < 4; j++) cval[r][wv*4 + j] = bv[j];
    cidx4[r][wv] = (unsigned int)bi[0] | ((unsigned int)bi[1] << 8)
                 | ((unsigned int)bi[2] << 16) | ((unsigned int)bi[3] << 24);
    __syncthreads();

    // ---- Phase C: wave0 merges 16 candidates per row + softmax ----
    if (tid < 64) {
        float mv[4] = {-3.0e38f, -3.0e38f, -3.0e38f, -3.0e38f};
        int   mi[4] = {0, 0, 0, 0};
        #pragma unroll
        for (int w4 = 0; w4 < 4; w4++) {
            unsigned int ip = cidx4[tid][w4];
            #pragma unroll
            for (int j = 0; j < 4; j++) {
                float x = cval[tid][w4*4 + j];
                int ix = (int)((ip >> (8*j)) & 255u);
                if (x > mv[3]) {
                    if (x > mv[1]) {
                        if (x > mv[0]) { mv[3]=mv[2];mi[3]=mi[2]; mv[2]=mv[1];mi[2]=mi[1]; mv[1]=mv[0];mi[1]=mi[0]; mv[0]=x; mi[0]=ix; }
                        else           { mv[3]=mv[2];mi[3]=mi[2]; mv[2]=mv[1];mi[2]=mi[1]; mv[1]=x; mi[1]=ix; }
                    } else {
                        if (x > mv[2]) { mv[3]=mv[2];mi[3]=mi[2]; mv[2]=x; mi[2]=ix; }
                        else           { mv[3]=x; mi[3]=ix; }
                    }
                }
            }
        }
        float m = mv[0];
        float e0 = __expf(mv[0]-m), e1 = __expf(mv[1]-m), e2 = __expf(mv[2]-m), e3 = __expf(mv[3]-m);
        float inv = 1.0f / (e0 + e1 + e2 + e3);
        float4 w; w.x = e0*inv; w.y = e1*inv; w.z = e2*inv; w.w = e3*inv;
        wts4[tid] = w;
        dpack[tid] = (unsigned int)mi[0] | ((unsigned int)mi[1] << 8)
                   | ((unsigned int)mi[2] << 16) | ((unsigned int)mi[3] << 24);
    }
    __syncthreads();

    // ---- Phase D: rows 16*wv..16*wv+15, lane = e; rotated v from GLOBAL ----
    {
        const int lane = tid & 63;
        const float* vbase = vg_ + rowbase * NE;
        float* obase = outV + rowbase * NE;
        #pragma unroll
        for (int t = 0; t < 16; t++) {
            const int rr = wv * 16 + t;
            float4 w4 = wts4[rr];
            unsigned int dp = dpack[rr];
            const float* vr = vbase + rr * NE;
            int dl0 = (int)(dp & 63u);
            int dl1 = (int)((dp >> 8) & 63u);
            int dl2 = (int)((dp >> 16) & 63u);
            int dl3 = (int)((dp >> 24) & 63u);
            float o;
            o = w4.x * vr[(lane + dl0) & 63];
            o = fmaf(w4.y, vr[(lane + dl1) & 63], o);
            o = fmaf(w4.z, vr[(lane + dl2) & 63], o);
            o = fmaf(w4.w, vr[(lane + dl3) & 63], o);
            obase[rr * NE + lane] = o;
        }
    }
}

extern "C" void kernel_launch(void* const* d_in, const int* in_sizes, int n_in,
                              void* d_out, int out_size, void* d_ws, size_t ws_size,
                              hipStream_t stream) {
    const float* q = (const float*)d_in[0];
    const float* k = (const float*)d_in[1];
    const float* v = (const float*)d_in[2];
    float* outV = (float*)d_out;
    float* outC = outV + (size_t)NB * NH * NL * NE;   // V first, then transposed corr
    dim3 grid(NB * NH * (NL / 64));                   // 8192 blocks
    autocorr_kernel<<<grid, 256, 0, stream>>>(q, k, v, outV, outC);
}